// Round 2
// baseline (197.885 us; speedup 1.0000x reference)
//
#include <hip/hip_runtime.h>
#include <hip/hip_bf16.h>
#include <stdint.h>

typedef __attribute__((ext_vector_type(8))) short s16x8;
typedef __attribute__((ext_vector_type(4))) float f32x4;

__device__ __forceinline__ unsigned short f2bfu(float x) {
  __hip_bfloat16 b = __float2bfloat16(x);
  return *reinterpret_cast<unsigned short*>(&b);
}

// ---------------- transpose + downcast: dst[C][R] = bf16(src[R][C]) ----------
__global__ __launch_bounds__(256) void transpose_k(const float* __restrict__ src,
                                                   unsigned short* __restrict__ dst,
                                                   int R, int C) {
  __shared__ float t[32][33];
  const int c0 = blockIdx.x * 32, r0 = blockIdx.y * 32;
  const int tx = threadIdx.x & 31, ty = threadIdx.x >> 5;
#pragma unroll
  for (int i = 0; i < 32; i += 8)
    t[ty + i][tx] = src[(size_t)(r0 + ty + i) * C + (c0 + tx)];
  __syncthreads();
#pragma unroll
  for (int i = 0; i < 32; i += 8)
    dst[(size_t)(c0 + ty + i) * R + (r0 + tx)] = f2bfu(t[tx][ty + i]);
}

// ---------------- per-batch precompute (all f32) ----------------
// blocks 0..255: batch b -> w[256], P[1024], R[1024]
// block 256: C[k] = gamma*(bv@W1)[k] + b1[k]
__global__ __launch_bounds__(256) void precompute_k(
    const float* __restrict__ X0,  // [256][512]
    const float* __restrict__ Xs,  // [256][255]
    const float* __restrict__ Wq,  // [512][64]
    const float* __restrict__ bq,  // [64]
    const float* __restrict__ Wk,  // [512][64]
    const float* __restrict__ bk,  // [64] (unused: cancels in softmax)
    const float* __restrict__ Wv,  // [512][512]
    const float* __restrict__ bv,  // [512]
    const float* __restrict__ gp,  // [1]
    const float* __restrict__ W1,  // [512][1024]
    const float* __restrict__ b1,  // [1024]
    float* __restrict__ Cws, float* __restrict__ Wws,
    float* __restrict__ Pws, float* __restrict__ Rws) {
  const int t = threadIdx.x;
  const int blk = blockIdx.x;
  __shared__ float x0f[512];
  __shared__ float v0f[512];
  __shared__ float sv[256];
  __shared__ float q0[64], k0s[64];
  __shared__ float scal[4];  // alpha, gamma2, smax, smin

  if (blk == 256) {
    const float g = gp[0];
    x0f[t] = bv[t];
    x0f[t + 256] = bv[t + 256];
    __syncthreads();
    float a0 = 0, a1 = 0, a2 = 0, a3 = 0;
    for (int d = 0; d < 512; ++d) {
      const float4 w = *reinterpret_cast<const float4*>(&W1[d * 1024 + 4 * t]);
      const float x = x0f[d];
      a0 = fmaf(x, w.x, a0);
      a1 = fmaf(x, w.y, a1);
      a2 = fmaf(x, w.z, a2);
      a3 = fmaf(x, w.w, a3);
    }
    Cws[4 * t + 0] = fmaf(g, a0, b1[4 * t + 0]);
    Cws[4 * t + 1] = fmaf(g, a1, b1[4 * t + 1]);
    Cws[4 * t + 2] = fmaf(g, a2, b1[4 * t + 2]);
    Cws[4 * t + 3] = fmaf(g, a3, b1[4 * t + 3]);
    return;
  }
  const int b = blk;
  x0f[t] = X0[b * 512 + t];
  x0f[t + 256] = X0[b * 512 + 256 + t];
  sv[t] = (t == 0) ? 1.0f : Xs[b * 255 + t - 1];
  __syncthreads();
  if (t < 128) {  // q0 / k0
    const float* W = (t < 64) ? Wq : Wk;
    const int j = t & 63;
    float a = 0;
    for (int d = 0; d < 512; ++d) a = fmaf(x0f[d], W[d * 64 + j], a);
    if (t < 64) q0[j] = a; else k0s[j] = a;
  }
  {  // v0 = x0 @ Wv
    float a0 = 0, a1 = 0;
    for (int d = 0; d < 512; ++d) {
      const float2 w = *reinterpret_cast<const float2*>(&Wv[d * 512 + 2 * t]);
      const float x = x0f[d];
      a0 = fmaf(x, w.x, a0);
      a1 = fmaf(x, w.y, a1);
    }
    v0f[2 * t] = a0;
    v0f[2 * t + 1] = a1;
  }
  __syncthreads();
  if (t == 0) {
    float al = 0, g2 = 0;
    for (int j = 0; j < 64; ++j) {
      al = fmaf(q0[j], k0s[j], al);
      g2 = fmaf(bq[j], k0s[j], g2);
    }
    float mx = sv[0], mn = sv[0];
    for (int m = 1; m < 256; ++m) { mx = fmaxf(mx, sv[m]); mn = fminf(mn, sv[m]); }
    scal[0] = al; scal[1] = g2; scal[2] = mx; scal[3] = mn;
  }
  __syncthreads();
  {  // w_n = sum_m softmax_m((alpha*s_n+g2)*s_m) * s_m   (thread t = n)
    const float c = fmaf(scal[0], sv[t], scal[1]);
    const float M = (c >= 0.f) ? c * scal[2] : c * scal[3];
    float Z = 0, Wm = 0;
    for (int m = 0; m < 256; ++m) {
      const float e = __expf(fmaf(c, sv[m], -M));
      Z += e;
      Wm = fmaf(sv[m], e, Wm);
    }
    Wws[b * 256 + t] = Wm / Z;
  }
  {  // P = v0@W1, R = x0@W1 (thread t: cols 4t..4t+3, share W1 load)
    float p0 = 0, p1 = 0, p2 = 0, p3 = 0, r0 = 0, r1 = 0, r2 = 0, r3 = 0;
    for (int d = 0; d < 512; ++d) {
      const float4 w = *reinterpret_cast<const float4*>(&W1[d * 1024 + 4 * t]);
      const float xv = x0f[d], vv = v0f[d];
      p0 = fmaf(vv, w.x, p0); p1 = fmaf(vv, w.y, p1);
      p2 = fmaf(vv, w.z, p2); p3 = fmaf(vv, w.w, p3);
      r0 = fmaf(xv, w.x, r0); r1 = fmaf(xv, w.y, r1);
      r2 = fmaf(xv, w.z, r2); r3 = fmaf(xv, w.w, r3);
    }
    float* Pp = Pws + b * 1024 + 4 * t;
    float* Rp = Rws + b * 1024 + 4 * t;
    Pp[0] = p0; Pp[1] = p1; Pp[2] = p2; Pp[3] = p3;
    Rp[0] = r0; Rp[1] = r1; Rp[2] = r2; Rp[3] = r3;
  }
}

// ---------------- GEMM1: h2 = relu(h1 @ W2 + b2), h1 generated on the fly ----
// BM=128 BN=512 BK=32, 512 threads (8 waves, 2x4), wave tile 64x128
__global__ __launch_bounds__(512) void gemm1_k(
    const float* __restrict__ Xs,
    const float* __restrict__ gp,
    const unsigned short* __restrict__ W2T,  // [512][1024] = bf16(W2^T)
    const float* __restrict__ b2,            // [512]
    const float* __restrict__ Cws, const float* __restrict__ Wws,
    const float* __restrict__ Pws, const float* __restrict__ Rws,
    unsigned short* __restrict__ h2)         // [65536][512] bf16
{
  __shared__ unsigned short At[2][128 * 32];  // 8KB each
  __shared__ unsigned short Bt[2][512 * 32];  // 32KB each
  const int tid = threadIdx.x;
  const int lane = tid & 63;
  const int wid = tid >> 6;
  const int wr = wid >> 2, wc = wid & 3;
  const int m0 = blockIdx.x * 128;
  const int b = m0 >> 8;
  // A-generation assignment: 4 threads per row, 8 k each
  const int r = tid >> 2, ks = tid & 3;
  const int n = (m0 + r) & 255;
  const float g = gp[0];
  const float gw = g * Wws[b * 256 + n];
  const float sr = (n == 0) ? 1.0f : Xs[b * 255 + n - 1];
  const float* Pp = Pws + b * 1024 + ks * 8;
  const float* Rp = Rws + b * 1024 + ks * 8;
  const float* Cp = Cws + ks * 8;
  const int aoff = tid * 8;             // elem offset of this thread's A chunk
  const int bbase = (tid & ~63) * 8;    // wave-uniform Bt chunk base (elems)

  f32x4 acc[4][8];
#pragma unroll
  for (int m = 0; m < 4; ++m)
#pragma unroll
    for (int nf = 0; nf < 8; ++nf) acc[m][nf] = (f32x4){0.f, 0.f, 0.f, 0.f};

  auto stage = [&](int buf, int k0) {
    // B tile: [512 rows][32 k] via global_load_lds (4 chunks/thread)
#pragma unroll
    for (int i = 0; i < 4; ++i) {
      const int c = i * 512 + tid;
      const int row = c >> 2, slot = c & 3;
      const unsigned short* src = W2T + row * 1024 + k0 + slot * 8;
      __builtin_amdgcn_global_load_lds(
          (const __attribute__((address_space(1))) void*)src,
          (__attribute__((address_space(3))) void*)&Bt[buf][i * 4096 + bbase],
          16, 0, 0);
    }
    // A tile: generated from rank-2 form, 8 bf16/thread -> one ds_write_b128
    const float4 p0 = *reinterpret_cast<const float4*>(Pp + k0);
    const float4 p1 = *reinterpret_cast<const float4*>(Pp + k0 + 4);
    const float4 r0 = *reinterpret_cast<const float4*>(Rp + k0);
    const float4 r1 = *reinterpret_cast<const float4*>(Rp + k0 + 4);
    const float4 c0 = *reinterpret_cast<const float4*>(Cp + k0);
    const float4 c1 = *reinterpret_cast<const float4*>(Cp + k0 + 4);
    s16x8 av;
    av[0] = (short)f2bfu(fmaxf(fmaf(gw, p0.x, fmaf(sr, r0.x, c0.x)), 0.f));
    av[1] = (short)f2bfu(fmaxf(fmaf(gw, p0.y, fmaf(sr, r0.y, c0.y)), 0.f));
    av[2] = (short)f2bfu(fmaxf(fmaf(gw, p0.z, fmaf(sr, r0.z, c0.z)), 0.f));
    av[3] = (short)f2bfu(fmaxf(fmaf(gw, p0.w, fmaf(sr, r0.w, c0.w)), 0.f));
    av[4] = (short)f2bfu(fmaxf(fmaf(gw, p1.x, fmaf(sr, r1.x, c1.x)), 0.f));
    av[5] = (short)f2bfu(fmaxf(fmaf(gw, p1.y, fmaf(sr, r1.y, c1.y)), 0.f));
    av[6] = (short)f2bfu(fmaxf(fmaf(gw, p1.z, fmaf(sr, r1.z, c1.z)), 0.f));
    av[7] = (short)f2bfu(fmaxf(fmaf(gw, p1.w, fmaf(sr, r1.w, c1.w)), 0.f));
    *reinterpret_cast<s16x8*>(&At[buf][aoff]) = av;
  };

  stage(0, 0);
  __syncthreads();
  const int ka = (lane >> 4) * 8;
  const int la = lane & 15;
  for (int step = 0; step < 32; ++step) {
    const int cur = step & 1;
    if (step + 1 < 32) stage(cur ^ 1, (step + 1) * 32);
    s16x8 af[4], bfr[8];
#pragma unroll
    for (int m = 0; m < 4; ++m)
      af[m] = *reinterpret_cast<const s16x8*>(&At[cur][(wr * 64 + m * 16 + la) * 32 + ka]);
#pragma unroll
    for (int nf = 0; nf < 8; ++nf)
      bfr[nf] = *reinterpret_cast<const s16x8*>(&Bt[cur][(wc * 128 + nf * 16 + la) * 32 + ka]);
#pragma unroll
    for (int m = 0; m < 4; ++m)
#pragma unroll
      for (int nf = 0; nf < 8; ++nf)
        acc[m][nf] = __builtin_amdgcn_mfma_f32_16x16x32_bf16(af[m], bfr[nf], acc[m][nf], 0, 0, 0);
    __syncthreads();
  }
  // epilogue: +b2, relu, bf16 store
  const int rq = (lane >> 4) * 4;
#pragma unroll
  for (int nf = 0; nf < 8; ++nf) {
    const int gn = wc * 128 + nf * 16 + la;
    const float bb = b2[gn];
#pragma unroll
    for (int m = 0; m < 4; ++m) {
      const int gmb = m0 + wr * 64 + m * 16 + rq;
#pragma unroll
      for (int q = 0; q < 4; ++q) {
        const float v = fmaxf(acc[m][nf][q] + bb, 0.f);
        h2[(size_t)(gmb + q) * 512 + gn] = f2bfu(v);
      }
    }
  }
}

// ---------------- GEMM2: out = relu(h2 @ W3 + b3), f32 out ----------------
// BM=128 BN=128 BK=32, 256 threads (4 waves, 2x2), wave tile 64x64
__global__ __launch_bounds__(256) void gemm2_k(
    const unsigned short* __restrict__ h2,   // [65536][512] bf16
    const unsigned short* __restrict__ W3T,  // [128][512] = bf16(W3^T)
    const float* __restrict__ b3,            // [128]
    float* __restrict__ out)                 // [65536][128] f32
{
  __shared__ unsigned short At[2][128 * 32];
  __shared__ unsigned short Bt[2][128 * 32];
  const int tid = threadIdx.x;
  const int lane = tid & 63;
  const int wid = tid >> 6;
  const int wr = wid >> 1, wc = wid & 1;
  const int m0 = blockIdx.x * 128;
  const int base = (tid & ~63) * 8;

  f32x4 acc[4][4];
#pragma unroll
  for (int m = 0; m < 4; ++m)
#pragma unroll
    for (int nf = 0; nf < 4; ++nf) acc[m][nf] = (f32x4){0.f, 0.f, 0.f, 0.f};

  auto stage = [&](int buf, int k0) {
#pragma unroll
    for (int i = 0; i < 2; ++i) {
      const int c = i * 256 + tid;
      const int row = c >> 2, slot = c & 3;
      __builtin_amdgcn_global_load_lds(
          (const __attribute__((address_space(1))) void*)(h2 + (size_t)(m0 + row) * 512 + k0 + slot * 8),
          (__attribute__((address_space(3))) void*)&At[buf][i * 2048 + base], 16, 0, 0);
    }
#pragma unroll
    for (int i = 0; i < 2; ++i) {
      const int c = i * 256 + tid;
      const int row = c >> 2, slot = c & 3;
      __builtin_amdgcn_global_load_lds(
          (const __attribute__((address_space(1))) void*)(W3T + row * 512 + k0 + slot * 8),
          (__attribute__((address_space(3))) void*)&Bt[buf][i * 2048 + base], 16, 0, 0);
    }
  };

  stage(0, 0);
  __syncthreads();
  const int ka = (lane >> 4) * 8;
  const int la = lane & 15;
  for (int step = 0; step < 16; ++step) {
    const int cur = step & 1;
    if (step + 1 < 16) stage(cur ^ 1, (step + 1) * 32);
    s16x8 af[4], bfr[4];
#pragma unroll
    for (int m = 0; m < 4; ++m)
      af[m] = *reinterpret_cast<const s16x8*>(&At[cur][(wr * 64 + m * 16 + la) * 32 + ka]);
#pragma unroll
    for (int nf = 0; nf < 4; ++nf)
      bfr[nf] = *reinterpret_cast<const s16x8*>(&Bt[cur][(wc * 64 + nf * 16 + la) * 32 + ka]);
#pragma unroll
    for (int m = 0; m < 4; ++m)
#pragma unroll
      for (int nf = 0; nf < 4; ++nf)
        acc[m][nf] = __builtin_amdgcn_mfma_f32_16x16x32_bf16(af[m], bfr[nf], acc[m][nf], 0, 0, 0);
    __syncthreads();
  }
  const int rq = (lane >> 4) * 4;
#pragma unroll
  for (int nf = 0; nf < 4; ++nf) {
    const int gn = wc * 64 + nf * 16 + la;
    const float bb = b3[gn];
#pragma unroll
    for (int m = 0; m < 4; ++m) {
      const int gmb = m0 + wr * 64 + m * 16 + rq;
#pragma unroll
      for (int q = 0; q < 4; ++q) {
        const float v = fmaxf(acc[m][nf][q] + bb, 0.f);
        out[(size_t)(gmb + q) * 128 + gn] = v;
      }
    }
  }
}

extern "C" void kernel_launch(void* const* d_in, const int* in_sizes, int n_in,
                              void* d_out, int out_size, void* d_ws, size_t ws_size,
                              hipStream_t stream) {
  const float* X0 = (const float*)d_in[0];
  const float* Xs = (const float*)d_in[1];
  const float* Wq = (const float*)d_in[2];
  const float* bq = (const float*)d_in[3];
  const float* Wk = (const float*)d_in[4];
  const float* bk = (const float*)d_in[5];
  const float* Wv = (const float*)d_in[6];
  const float* bv = (const float*)d_in[7];
  const float* gp = (const float*)d_in[8];
  const float* W1 = (const float*)d_in[9];
  const float* b1 = (const float*)d_in[10];
  const float* W2 = (const float*)d_in[11];
  const float* b2 = (const float*)d_in[12];
  const float* W3 = (const float*)d_in[13];
  const float* b3 = (const float*)d_in[14];

  char* ws = (char*)d_ws;
  float* Cws = (float*)(ws);                         //   4 KB
  float* Wws = (float*)(ws + 4096);                  // 256 KB
  float* Pws = (float*)(ws + 266240);                //   1 MB
  float* Rws = (float*)(ws + 1314816);               //   1 MB
  unsigned short* W2T = (unsigned short*)(ws + 2363392);  // 1 MB (bf16)
  unsigned short* W3T = (unsigned short*)(ws + 3411968);  // 128 KB (bf16)
  unsigned short* h2  = (unsigned short*)(ws + 3543040);  // 64 MB (bf16)
  float* out = (float*)d_out;

  hipLaunchKernelGGL(transpose_k, dim3(16, 32), dim3(256), 0, stream, W2, W2T, 1024, 512);
  hipLaunchKernelGGL(transpose_k, dim3(4, 16), dim3(256), 0, stream, W3, W3T, 512, 128);
  hipLaunchKernelGGL(precompute_k, dim3(257), dim3(256), 0, stream,
                     X0, Xs, Wq, bq, Wk, bk, Wv, bv, gp, W1, b1, Cws, Wws, Pws, Rws);
  hipLaunchKernelGGL(gemm1_k, dim3(512), dim3(512), 0, stream,
                     Xs, gp, W2T, b2, Cws, Wws, Pws, Rws, h2);
  hipLaunchKernelGGL(gemm2_k, dim3(512), dim3(256), 0, stream, h2, W3T, b3, out);
}

// Round 3
// 184.516 us; speedup vs baseline: 1.0725x; 1.0725x over previous
//
#include <hip/hip_runtime.h>
#include <hip/hip_bf16.h>

typedef __attribute__((ext_vector_type(8))) short s16x8;
typedef __attribute__((ext_vector_type(4))) float f32x4;

__device__ __forceinline__ unsigned short f2bfu(float x) {
  __hip_bfloat16 b = __float2bfloat16(x);
  return *reinterpret_cast<unsigned short*>(&b);
}

// ---------------- transpose + downcast: dst[C][R] = bf16(src[R][C]) ----------
__global__ __launch_bounds__(256) void transpose_k(const float* __restrict__ src,
                                                   unsigned short* __restrict__ dst,
                                                   int R, int C) {
  __shared__ float t[32][33];
  const int c0 = blockIdx.x * 32, r0 = blockIdx.y * 32;
  const int tx = threadIdx.x & 31, ty = threadIdx.x >> 5;
#pragma unroll
  for (int i = 0; i < 32; i += 8)
    t[ty + i][tx] = src[(size_t)(r0 + ty + i) * C + (c0 + tx)];
  __syncthreads();
#pragma unroll
  for (int i = 0; i < 32; i += 8)
    dst[(size_t)(c0 + ty + i) * R + (r0 + tx)] = f2bfu(t[tx][ty + i]);
}

// ---------------- per-batch precompute (all f32) ----------------
__global__ __launch_bounds__(256) void precompute_k(
    const float* __restrict__ X0, const float* __restrict__ Xs,
    const float* __restrict__ Wq, const float* __restrict__ bq,
    const float* __restrict__ Wk, const float* __restrict__ bk,
    const float* __restrict__ Wv, const float* __restrict__ bv,
    const float* __restrict__ gp, const float* __restrict__ W1,
    const float* __restrict__ b1,
    float* __restrict__ Cws, float* __restrict__ Wws,
    float* __restrict__ Pws, float* __restrict__ Rws) {
  const int t = threadIdx.x;
  const int blk = blockIdx.x;
  __shared__ float x0f[512];
  __shared__ float v0f[512];
  __shared__ float sv[256];
  __shared__ float q0[64], k0s[64];
  __shared__ float scal[4];

  if (blk == 256) {
    const float g = gp[0];
    x0f[t] = bv[t];
    x0f[t + 256] = bv[t + 256];
    __syncthreads();
    float a0 = 0, a1 = 0, a2 = 0, a3 = 0;
    for (int d = 0; d < 512; ++d) {
      const float4 w = *reinterpret_cast<const float4*>(&W1[d * 1024 + 4 * t]);
      const float x = x0f[d];
      a0 = fmaf(x, w.x, a0);
      a1 = fmaf(x, w.y, a1);
      a2 = fmaf(x, w.z, a2);
      a3 = fmaf(x, w.w, a3);
    }
    Cws[4 * t + 0] = fmaf(g, a0, b1[4 * t + 0]);
    Cws[4 * t + 1] = fmaf(g, a1, b1[4 * t + 1]);
    Cws[4 * t + 2] = fmaf(g, a2, b1[4 * t + 2]);
    Cws[4 * t + 3] = fmaf(g, a3, b1[4 * t + 3]);
    return;
  }
  const int b = blk;
  x0f[t] = X0[b * 512 + t];
  x0f[t + 256] = X0[b * 512 + 256 + t];
  sv[t] = (t == 0) ? 1.0f : Xs[b * 255 + t - 1];
  __syncthreads();
  if (t < 128) {
    const float* W = (t < 64) ? Wq : Wk;
    const int j = t & 63;
    float a = 0;
    for (int d = 0; d < 512; ++d) a = fmaf(x0f[d], W[d * 64 + j], a);
    if (t < 64) q0[j] = a; else k0s[j] = a;
  }
  {
    float a0 = 0, a1 = 0;
    for (int d = 0; d < 512; ++d) {
      const float2 w = *reinterpret_cast<const float2*>(&Wv[d * 512 + 2 * t]);
      const float x = x0f[d];
      a0 = fmaf(x, w.x, a0);
      a1 = fmaf(x, w.y, a1);
    }
    v0f[2 * t] = a0;
    v0f[2 * t + 1] = a1;
  }
  __syncthreads();
  if (t == 0) {
    float al = 0, g2 = 0;
    for (int j = 0; j < 64; ++j) {
      al = fmaf(q0[j], k0s[j], al);
      g2 = fmaf(bq[j], k0s[j], g2);
    }
    float mx = sv[0], mn = sv[0];
    for (int m = 1; m < 256; ++m) { mx = fmaxf(mx, sv[m]); mn = fminf(mn, sv[m]); }
    scal[0] = al; scal[1] = g2; scal[2] = mx; scal[3] = mn;
  }
  __syncthreads();
  {
    const float c = fmaf(scal[0], sv[t], scal[1]);
    const float M = (c >= 0.f) ? c * scal[2] : c * scal[3];
    float Z = 0, Wm = 0;
    for (int m = 0; m < 256; ++m) {
      const float e = __expf(fmaf(c, sv[m], -M));
      Z += e;
      Wm = fmaf(sv[m], e, Wm);
    }
    Wws[b * 256 + t] = Wm / Z;
  }
  {
    float p0 = 0, p1 = 0, p2 = 0, p3 = 0, r0 = 0, r1 = 0, r2 = 0, r3 = 0;
    for (int d = 0; d < 512; ++d) {
      const float4 w = *reinterpret_cast<const float4*>(&W1[d * 1024 + 4 * t]);
      const float xv = x0f[d], vv = v0f[d];
      p0 = fmaf(vv, w.x, p0); p1 = fmaf(vv, w.y, p1);
      p2 = fmaf(vv, w.z, p2); p3 = fmaf(vv, w.w, p3);
      r0 = fmaf(xv, w.x, r0); r1 = fmaf(xv, w.y, r1);
      r2 = fmaf(xv, w.z, r2); r3 = fmaf(xv, w.w, r3);
    }
    float* Pp = Pws + b * 1024 + 4 * t;
    float* Rp = Rws + b * 1024 + 4 * t;
    Pp[0] = p0; Pp[1] = p1; Pp[2] = p2; Pp[3] = p3;
    Rp[0] = r0; Rp[1] = r1; Rp[2] = r2; Rp[3] = r3;
  }
}

// ---------------- fused GEMM: out = relu(relu(h1@W2+b2)@W3 + b3) -------------
// h1 generated from rank-2 form. BM=128, BN=512, BK=32, 512 thr (8 waves 2x4).
// LDS layout is [k-slot j][row][8elem] everywhere -> conflict-free b128 frags.
// smem elems (ushort):
//   Bt[buf]: buf*16384 + j*4096 + row*8    (j 0..3, row 0..511)  [0, 32768)
//   At[buf]: 32768 + buf*4096 + j*1024 + row*8 (row 0..127)      [32768, 40960)
//   h2t    : j2*1024 + row*8               (j2 0..63, row 0..127)[0, 65536)
//   W3c[buf]: 65536 + buf*4096 + j*1024 + row*8 (row 0..127)     [65536, 73728)
__global__ __launch_bounds__(512, 2) void fused_k(
    const float* __restrict__ Xs, const float* __restrict__ gp,
    const unsigned short* __restrict__ W2T,  // [512][1024] bf16
    const float* __restrict__ b2,
    const unsigned short* __restrict__ W3T,  // [128][512] bf16
    const float* __restrict__ b3,
    const float* __restrict__ Cws, const float* __restrict__ Wws,
    const float* __restrict__ Pws, const float* __restrict__ Rws,
    float* __restrict__ out)  // [65536][128] f32
{
  __shared__ __align__(16) unsigned short smem_u[73728];  // 144 KB
  const int tid = threadIdx.x;
  const int lane = tid & 63;
  const int wid = tid >> 6;
  const int wr = wid >> 2, wc = wid & 3;
  const int la = lane & 15;
  const int q4 = lane >> 4;
  const int m0 = blockIdx.x * 128;
  const int b = m0 >> 8;
  // staging thread mapping: 4 threads per A-row (r), k-slot ks
  const int r = tid >> 2, ks = tid & 3;
  const int n_tok = (m0 + r) & 255;
  const float g = gp[0];
  const float gw = g * Wws[b * 256 + n_tok];
  const float sr = (n_tok == 0) ? 1.0f : Xs[b * 255 + n_tok - 1];
  const float* Pp = Pws + b * 1024 + ks * 8;
  const float* Rp = Rws + b * 1024 + ks * 8;
  const float* Cp = Cws + ks * 8;

  auto agen = [&](int k0) -> s16x8 {
    const float4 p0 = *reinterpret_cast<const float4*>(Pp + k0);
    const float4 p1 = *reinterpret_cast<const float4*>(Pp + k0 + 4);
    const float4 r0 = *reinterpret_cast<const float4*>(Rp + k0);
    const float4 r1 = *reinterpret_cast<const float4*>(Rp + k0 + 4);
    const float4 c0 = *reinterpret_cast<const float4*>(Cp + k0);
    const float4 c1 = *reinterpret_cast<const float4*>(Cp + k0 + 4);
    s16x8 av;
    av[0] = (short)f2bfu(fmaxf(fmaf(gw, p0.x, fmaf(sr, r0.x, c0.x)), 0.f));
    av[1] = (short)f2bfu(fmaxf(fmaf(gw, p0.y, fmaf(sr, r0.y, c0.y)), 0.f));
    av[2] = (short)f2bfu(fmaxf(fmaf(gw, p0.z, fmaf(sr, r0.z, c0.z)), 0.f));
    av[3] = (short)f2bfu(fmaxf(fmaf(gw, p0.w, fmaf(sr, r0.w, c0.w)), 0.f));
    av[4] = (short)f2bfu(fmaxf(fmaf(gw, p1.x, fmaf(sr, r1.x, c1.x)), 0.f));
    av[5] = (short)f2bfu(fmaxf(fmaf(gw, p1.y, fmaf(sr, r1.y, c1.y)), 0.f));
    av[6] = (short)f2bfu(fmaxf(fmaf(gw, p1.z, fmaf(sr, r1.z, c1.z)), 0.f));
    av[7] = (short)f2bfu(fmaxf(fmaf(gw, p1.w, fmaf(sr, r1.w, c1.w)), 0.f));
    return av;
  };

  f32x4 acc[4][8];
#pragma unroll
  for (int m = 0; m < 4; ++m)
#pragma unroll
    for (int nf = 0; nf < 8; ++nf) acc[m][nf] = (f32x4){0.f, 0.f, 0.f, 0.f};

  // ---- phase A prologue: stage K-step 0 into buf 0 ----
  {
    s16x8 bst[4];
#pragma unroll
    for (int i = 0; i < 4; ++i)
      bst[i] = *reinterpret_cast<const s16x8*>(W2T + (size_t)(i * 128 + r) * 1024 + ks * 8);
    const s16x8 ast = agen(0);
#pragma unroll
    for (int i = 0; i < 4; ++i)
      *reinterpret_cast<s16x8*>(&smem_u[ks * 4096 + (i * 128 + r) * 8]) = bst[i];
    *reinterpret_cast<s16x8*>(&smem_u[32768 + ks * 1024 + r * 8]) = ast;
  }
  __syncthreads();

  // ---- phase A main loop: 32 K-steps ----
  for (int step = 0; step < 32; ++step) {
    const int cur = step & 1;
    const bool pre = (step + 1 < 32);
    s16x8 bst[4], ast;
    if (pre) {
      const int k0n = (step + 1) * 32;
#pragma unroll
      for (int i = 0; i < 4; ++i)
        bst[i] = *reinterpret_cast<const s16x8*>(W2T + (size_t)(i * 128 + r) * 1024 + k0n + ks * 8);
      ast = agen(k0n);
    }
    s16x8 af[4], bfr[8];
#pragma unroll
    for (int m = 0; m < 4; ++m)
      af[m] = *reinterpret_cast<const s16x8*>(
          &smem_u[32768 + cur * 4096 + q4 * 1024 + (wr * 64 + m * 16 + la) * 8]);
#pragma unroll
    for (int nf = 0; nf < 8; ++nf)
      bfr[nf] = *reinterpret_cast<const s16x8*>(
          &smem_u[cur * 16384 + q4 * 4096 + (wc * 128 + nf * 16 + la) * 8]);
#pragma unroll
    for (int m = 0; m < 4; ++m)
#pragma unroll
      for (int nf = 0; nf < 8; ++nf)
        acc[m][nf] = __builtin_amdgcn_mfma_f32_16x16x32_bf16(af[m], bfr[nf], acc[m][nf], 0, 0, 0);
    if (pre) {
      const int nb = cur ^ 1;
#pragma unroll
      for (int i = 0; i < 4; ++i)
        *reinterpret_cast<s16x8*>(&smem_u[nb * 16384 + ks * 4096 + (i * 128 + r) * 8]) = bst[i];
      *reinterpret_cast<s16x8*>(&smem_u[32768 + nb * 4096 + ks * 1024 + r * 8]) = ast;
    }
    __syncthreads();
  }

  // ---- transition: h2 tile (bias+relu, bf16) -> h2t in [j2][row] layout ----
  const int rq = q4 * 4;
#pragma unroll
  for (int nf = 0; nf < 8; ++nf) {
    const int n = wc * 128 + nf * 16 + la;
    const float bb = b2[n];
    const int jcol = n >> 3, ncol = n & 7;
#pragma unroll
    for (int m = 0; m < 4; ++m) {
      const int row0 = wr * 64 + m * 16 + rq;
#pragma unroll
      for (int qq = 0; qq < 4; ++qq)
        smem_u[jcol * 1024 + (row0 + qq) * 8 + ncol] =
            f2bfu(fmaxf(acc[m][nf][qq] + bb, 0.f));
    }
  }
  // stage W3 chunk 0 (region disjoint from h2t)
  {
    const s16x8 wst = *reinterpret_cast<const s16x8*>(W3T + (size_t)r * 512 + ks * 8);
    *reinterpret_cast<s16x8*>(&smem_u[65536 + ks * 1024 + r * 8]) = wst;
  }
  __syncthreads();

  // ---- phase B: out = relu(h2t @ W3 + b3), 128x128, K=512, 16 steps ----
  f32x4 acc2[4][2];
#pragma unroll
  for (int m = 0; m < 4; ++m)
#pragma unroll
    for (int nf = 0; nf < 2; ++nf) acc2[m][nf] = (f32x4){0.f, 0.f, 0.f, 0.f};

  for (int step = 0; step < 16; ++step) {
    const int cur = step & 1;
    const bool pre = (step + 1 < 16);
    s16x8 wst;
    if (pre)
      wst = *reinterpret_cast<const s16x8*>(W3T + (size_t)r * 512 + (step + 1) * 32 + ks * 8);
    s16x8 af2[4], bf2[2];
    const int j2b = step * 4 + q4;
#pragma unroll
    for (int m = 0; m < 4; ++m)
      af2[m] = *reinterpret_cast<const s16x8*>(
          &smem_u[j2b * 1024 + (wr * 64 + m * 16 + la) * 8]);
#pragma unroll
    for (int nf = 0; nf < 2; ++nf)
      bf2[nf] = *reinterpret_cast<const s16x8*>(
          &smem_u[65536 + cur * 4096 + q4 * 1024 + (wc * 32 + nf * 16 + la) * 8]);
#pragma unroll
    for (int m = 0; m < 4; ++m)
#pragma unroll
      for (int nf = 0; nf < 2; ++nf)
        acc2[m][nf] = __builtin_amdgcn_mfma_f32_16x16x32_bf16(af2[m], bf2[nf], acc2[m][nf], 0, 0, 0);
    if (pre)
      *reinterpret_cast<s16x8*>(&smem_u[65536 + (cur ^ 1) * 4096 + ks * 1024 + r * 8]) = wst;
    __syncthreads();
  }

  // ---- epilogue: f32 out ----
#pragma unroll
  for (int nf = 0; nf < 2; ++nf) {
    const int n = wc * 32 + nf * 16 + la;
    const float bb = b3[n];
#pragma unroll
    for (int m = 0; m < 4; ++m) {
      const int row0 = m0 + wr * 64 + m * 16 + rq;
#pragma unroll
      for (int qq = 0; qq < 4; ++qq)
        out[(size_t)(row0 + qq) * 128 + n] = fmaxf(acc2[m][nf][qq] + bb, 0.f);
    }
  }
}

extern "C" void kernel_launch(void* const* d_in, const int* in_sizes, int n_in,
                              void* d_out, int out_size, void* d_ws, size_t ws_size,
                              hipStream_t stream) {
  const float* X0 = (const float*)d_in[0];
  const float* Xs = (const float*)d_in[1];
  const float* Wq = (const float*)d_in[2];
  const float* bq = (const float*)d_in[3];
  const float* Wk = (const float*)d_in[4];
  const float* bk = (const float*)d_in[5];
  const float* Wv = (const float*)d_in[6];
  const float* bv = (const float*)d_in[7];
  const float* gp = (const float*)d_in[8];
  const float* W1 = (const float*)d_in[9];
  const float* b1 = (const float*)d_in[10];
  const float* W2 = (const float*)d_in[11];
  const float* b2 = (const float*)d_in[12];
  const float* W3 = (const float*)d_in[13];
  const float* b3 = (const float*)d_in[14];

  char* ws = (char*)d_ws;
  float* Cws = (float*)(ws);                              //   4 KB
  float* Wws = (float*)(ws + 4096);                       // 256 KB
  float* Pws = (float*)(ws + 266240);                     //   1 MB
  float* Rws = (float*)(ws + 1314816);                    //   1 MB
  unsigned short* W2T = (unsigned short*)(ws + 2363392);  //   1 MB (bf16)
  unsigned short* W3T = (unsigned short*)(ws + 3411968);  // 128 KB (bf16)
  float* out = (float*)d_out;

  hipLaunchKernelGGL(transpose_k, dim3(16, 32), dim3(256), 0, stream, W2, W2T, 1024, 512);
  hipLaunchKernelGGL(transpose_k, dim3(4, 16), dim3(256), 0, stream, W3, W3T, 512, 128);
  hipLaunchKernelGGL(precompute_k, dim3(257), dim3(256), 0, stream,
                     X0, Xs, Wq, bq, Wk, bk, Wv, bv, gp, W1, b1, Cws, Wws, Pws, Rws);
  hipLaunchKernelGGL(fused_k, dim3(512), dim3(512), 0, stream,
                     Xs, gp, W2T, b2, W3T, b3, Cws, Wws, Pws, Rws, out);
}